// Round 10
// baseline (325.134 us; speedup 1.0000x reference)
//
#include <hip/hip_runtime.h>

#define BB 32
#define TT 128
#define II 256
#define HH 256
#define OO 128
#define FWID 512  // H + I

// d_ws: u64 slots[2][BB][HH] (parity, batch, row) = 128 KB.
// Slot = (stamp<<32)|float_bits(h); step s consumes stamp>=s from parity s&1,
// publishes stamp s+1 into parity (s+1)&1. Agent-scope relaxed (no fences);
// protocol proven on HW in R2/R3/R5/R8.
// Overwrite safety: producer writes stamp s+2 (same parity slot as stamp s)
// only in step s+1, gated on its half's gather(s+1) = all 256 rows at stamp
// s+1 = every block of this batch exited its stamp-s gather loop. LDS lh[par]
// overwrite: gather(s) completion implies all publishers passed their
// consume(s-2) reads of lh[par]. u64 atomics cannot tear.
//
// R10 vs R8 (258 us): R9's two-independent-chains-per-CU idea inside the
// PROVEN 256-block cooperative launch (R9's 512-block coop launch never ran —
// grid > co-resident capacity is rejected). 1024-thread block = two fully
// independent 512-thread halves (batch pr / pr+16), separate gatherer wave,
// LDS buffers, flags; no __syncthreads after init. Per-batch gatherer fan-out
// stays 16 waves (R5/R8 fabric load — R6 showed more pollers congest IF).

typedef unsigned long long u64;

__device__ __forceinline__ u64 slot_ld(const u64* p) {
    return __hip_atomic_load(p, __ATOMIC_RELAXED, __HIP_MEMORY_SCOPE_AGENT);
}

// One wave gathers 256 rows of one batch (4 slots/lane, issued concurrently),
// stages h to LDS (ds_write_b128), release-stores an LDS flag.
__device__ __forceinline__ void gather_to_lds(const u64* base, int lane, unsigned us,
                                              float* dst, int* flag, int fval) {
    const u64* p = base + 4 * lane;
    u64 a, b, c, d;
    for (;;) {
        a = slot_ld(p);
        b = slot_ld(p + 1);
        c = slot_ld(p + 2);
        d = slot_ld(p + 3);
        bool ok = ((unsigned)(a >> 32) >= us) & ((unsigned)(b >> 32) >= us) &
                  ((unsigned)(c >> 32) >= us) & ((unsigned)(d >> 32) >= us);
        if (__all(ok)) break;
    }
    float4 hv;
    hv.x = __uint_as_float((unsigned)a);
    hv.y = __uint_as_float((unsigned)b);
    hv.z = __uint_as_float((unsigned)c);
    hv.w = __uint_as_float((unsigned)d);
    *reinterpret_cast<float4*>(dst + 4 * lane) = hv;
    if (lane == 0)  // release drains the wave's ds_write before the flag
        __hip_atomic_store(flag, fval, __ATOMIC_RELEASE, __HIP_MEMORY_SCOPE_WORKGROUP);
}

__global__ __launch_bounds__(1024, 4)
void stpn_kernel(const float* __restrict__ x,      // (B,T,I)
                 const float* __restrict__ wlam,   // (H,FWID)
                 const float* __restrict__ wgam,   // (H,FWID)
                 const float* __restrict__ w,      // (H,FWID)
                 const float* __restrict__ bias,   // (H)
                 const float* __restrict__ wout,   // (O,H)
                 const float* __restrict__ bout,   // (O)
                 float* __restrict__ out,          // tag(4096) | h_T(8192) | F_T
                 u64* __restrict__ slots)
{
    __shared__ __align__(16) float lh[2][2][HH];   // [half][parity][row]
    __shared__ int lflag[2][2];                    // [half][parity]

    const int tid  = threadIdx.x;
    const int bk   = blockIdx.x;
    const int pr   = bk & 15;        // batch pair: pr, pr+16
    const int sl   = bk >> 4;        // row slice 0..15
    const int half = tid >> 9;       // 0 / 1: independent sub-blocks
    const int t    = tid & 511;      // id within half
    const int b    = half ? pr + 16 : pr;
    const int wv   = t >> 6;         // wave-within-half 0..7
    const int lane = t & 63;
    const int hw   = lane >> 5;
    const int i    = lane & 31;
    const int r    = sl * 16 + wv * 2 + hw;

    if (tid < 4) ((int*)lflag)[tid] = 0;

    // Per-lane f-chunks of row r: f = 128*k + 4*i + c
    float4 W4[4], L4[4], G4[4], F4[4];
    {
        const float4* wr = reinterpret_cast<const float4*>(w    + (size_t)r * FWID);
        const float4* lr = reinterpret_cast<const float4*>(wlam + (size_t)r * FWID);
        const float4* gr = reinterpret_cast<const float4*>(wgam + (size_t)r * FWID);
#pragma unroll
        for (int k = 0; k < 4; ++k) {
            W4[k] = wr[k * 32 + i];
            L4[k] = lr[k * 32 + i];
            G4[k] = gr[k * 32 + i];
            F4[k] = make_float4(0.f, 0.f, 0.f, 0.f);
        }
    }
    const float bj = bias[r];
    float hl = 0.f;

    __syncthreads();   // lflag init visible; ONLY block-wide sync (all threads reach)

    for (int s = 0; s < TT; ++s) {
        const int par = s & 1;

        // x load (L2-resident after first pass)
        const float4* xb = reinterpret_cast<const float4*>(x + ((size_t)b * TT + s) * II);
        float4 T0 = xb[i], T1 = xb[32 + i];

        // ---- Phase P: independent of h(s), runs before the gather ----
        float4 tw2, tw3;
        float4 dx = make_float4(0,0,0,0), nv = make_float4(0,0,0,0);
        {
            float4 tt;
            tt.x = W4[0].x + F4[0].x; tt.y = W4[0].y + F4[0].y; tt.z = W4[0].z + F4[0].z; tt.w = W4[0].w + F4[0].w;
            dx.x = fmaf(T0.x, tt.x, dx.x); dx.y = fmaf(T0.y, tt.y, dx.y);
            dx.z = fmaf(T0.z, tt.z, dx.z); dx.w = fmaf(T0.w, tt.w, dx.w);
            nv.x = fmaf(tt.x, tt.x, nv.x); nv.y = fmaf(tt.y, tt.y, nv.y);
            nv.z = fmaf(tt.z, tt.z, nv.z); nv.w = fmaf(tt.w, tt.w, nv.w);
            tt.x = W4[1].x + F4[1].x; tt.y = W4[1].y + F4[1].y; tt.z = W4[1].z + F4[1].z; tt.w = W4[1].w + F4[1].w;
            dx.x = fmaf(T1.x, tt.x, dx.x); dx.y = fmaf(T1.y, tt.y, dx.y);
            dx.z = fmaf(T1.z, tt.z, dx.z); dx.w = fmaf(T1.w, tt.w, dx.w);
            nv.x = fmaf(tt.x, tt.x, nv.x); nv.y = fmaf(tt.y, tt.y, nv.y);
            nv.z = fmaf(tt.z, tt.z, nv.z); nv.w = fmaf(tt.w, tt.w, nv.w);
            tw2.x = W4[2].x + F4[2].x; tw2.y = W4[2].y + F4[2].y; tw2.z = W4[2].z + F4[2].z; tw2.w = W4[2].w + F4[2].w;
            nv.x = fmaf(tw2.x, tw2.x, nv.x); nv.y = fmaf(tw2.y, tw2.y, nv.y);
            nv.z = fmaf(tw2.z, tw2.z, nv.z); nv.w = fmaf(tw2.w, tw2.w, nv.w);
            tw3.x = W4[3].x + F4[3].x; tw3.y = W4[3].y + F4[3].y; tw3.z = W4[3].z + F4[3].z; tw3.w = W4[3].w + F4[3].w;
            nv.x = fmaf(tw3.x, tw3.x, nv.x); nv.y = fmaf(tw3.y, tw3.y, nv.y);
            nv.z = fmaf(tw3.z, tw3.z, nv.z); nv.w = fmaf(tw3.w, tw3.w, nv.w);
        }
        float dxs = (dx.x + dx.y) + (dx.z + dx.w);
        float nrm = (nv.x + nv.y) + (nv.z + nv.w);
#pragma unroll
        for (int off = 1; off <= 16; off <<= 1) {
            dxs += __shfl_xor(dxs, off, 64);
            nrm += __shfl_xor(nrm, off, 64);
        }
        const float invn = 1.0f / (sqrtf(nrm) + 1e-16f);

        // F decay + gamma*x (h-independent)
#pragma unroll
        for (int k = 0; k < 4; ++k) {
            F4[k].x = L4[k].x * (F4[k].x * invn); F4[k].y = L4[k].y * (F4[k].y * invn);
            F4[k].z = L4[k].z * (F4[k].z * invn); F4[k].w = L4[k].w * (F4[k].w * invn);
        }
        T0.x *= G4[0].x; T0.y *= G4[0].y; T0.z *= G4[0].z; T0.w *= G4[0].w;
        T1.x *= G4[1].x; T1.y *= G4[1].y; T1.z *= G4[1].z; T1.w *= G4[1].w;

        // ---- gather (wave 0 of this half, pipelined after Phase P) ----
        if (wv == 0) {
            gather_to_lds(slots + ((size_t)par * BB + b) * HH, lane,
                          (unsigned)s, lh[half][par], &lflag[half][par], s + 1);
        }

        // ---- Phase W: LDS flag spin, consume h ----
        while (__hip_atomic_load(&lflag[half][par], __ATOMIC_ACQUIRE, __HIP_MEMORY_SCOPE_WORKGROUP) <= s) {}
        const float4* lh4 = reinterpret_cast<const float4*>(lh[half][par]);
        float4 T2 = lh4[i], T3 = lh4[32 + i];

        float dh = fmaf(T2.x, tw2.x, fmaf(T2.y, tw2.y, fmaf(T2.z, tw2.z, T2.w * tw2.w)));
        dh = fmaf(T3.x, tw3.x, fmaf(T3.y, tw3.y, fmaf(T3.z, tw3.z, fmaf(T3.w, tw3.w, dh))));
#pragma unroll
        for (int off = 1; off <= 16; off <<= 1) dh += __shfl_xor(dh, off, 64);

        const float e = __expf(2.0f * (dxs + dh + bj));
        const float h = (1.0f - 2.0f / (e + 1.0f)) * invn;
        hl = h;

        // publish ASAP (relaxed agent store, no fence)
        if (i == 0) {
            __hip_atomic_store(slots + ((size_t)(par ^ 1) * BB + b) * HH + r,
                               ((u64)(unsigned)(s + 1) << 32) | (unsigned)__float_as_uint(h),
                               __ATOMIC_RELAXED, __HIP_MEMORY_SCOPE_AGENT);
        }

        // ---- Phase U: F += (gamma*t)*h ----
        F4[0].x = fmaf(T0.x, h, F4[0].x); F4[0].y = fmaf(T0.y, h, F4[0].y);
        F4[0].z = fmaf(T0.z, h, F4[0].z); F4[0].w = fmaf(T0.w, h, F4[0].w);
        F4[1].x = fmaf(T1.x, h, F4[1].x); F4[1].y = fmaf(T1.y, h, F4[1].y);
        F4[1].z = fmaf(T1.z, h, F4[1].z); F4[1].w = fmaf(T1.w, h, F4[1].w);
        F4[2].x = fmaf(G4[2].x * T2.x, h, F4[2].x); F4[2].y = fmaf(G4[2].y * T2.y, h, F4[2].y);
        F4[2].z = fmaf(G4[2].z * T2.z, h, F4[2].z); F4[2].w = fmaf(G4[2].w * T2.w, h, F4[2].w);
        F4[3].x = fmaf(G4[3].x * T3.x, h, F4[3].x); F4[3].y = fmaf(G4[3].y * T3.y, h, F4[3].y);
        F4[3].z = fmaf(G4[3].z * T3.z, h, F4[3].z); F4[3].w = fmaf(G4[3].w * T3.w, h, F4[3].w);
    }

    // ---- epilogue: F_T, h_T ----
    {
        float4* fo = reinterpret_cast<float4*>(out + 12288 + ((size_t)b * HH + r) * FWID);
#pragma unroll
        for (int k = 0; k < 4; ++k) fo[k * 32 + i] = F4[k];
    }
    if (i == 0) out[4096 + (size_t)b * HH + r] = hl;

    // tag_space: slice-0 blocks; each half gathers its batch's final h
    // (stamp TT, parity TT&1 == 0) and computes its batch's 128 outputs.
    if (sl == 0) {
        if (wv == 0) {
            gather_to_lds(slots + ((size_t)(TT & 1) * BB + b) * HH, lane,
                          (unsigned)TT, lh[half][0], &lflag[half][0], TT + 1);
        }
        while (__hip_atomic_load(&lflag[half][0], __ATOMIC_ACQUIRE, __HIP_MEMORY_SCOPE_WORKGROUP) <= TT) {}
        if (t < OO) {
            const float* hv = lh[half][0];
            float acc = bout[t];
            const float* wo = wout + (size_t)t * HH;
#pragma unroll 4
            for (int jj = 0; jj < HH; ++jj) acc = fmaf(wo[jj], hv[jj], acc);
            out[(size_t)b * OO + t] = acc;
        }
    }
}

extern "C" void kernel_launch(void* const* d_in, const int* in_sizes, int n_in,
                              void* d_out, int out_size, void* d_ws, size_t ws_size,
                              hipStream_t stream) {
    (void)in_sizes; (void)n_in; (void)out_size; (void)ws_size;
    const float* x    = (const float*)d_in[0];
    const float* wlam = (const float*)d_in[1];
    const float* wgam = (const float*)d_in[2];
    const float* w    = (const float*)d_in[3];
    const float* bias = (const float*)d_in[4];
    const float* wout = (const float*)d_in[5];
    const float* bout = (const float*)d_in[6];
    float* out = (float*)d_out;

    u64* slots = (u64*)d_ws;

    // stamp 0 + h = 0.0 is exactly what step 0 consumes
    hipMemsetAsync(d_ws, 0, 2ull * BB * HH * 8ull, stream);

    void* args[] = {(void*)&x, (void*)&wlam, (void*)&wgam, (void*)&w, (void*)&bias,
                    (void*)&wout, (void*)&bout, (void*)&out, (void*)&slots};
    hipLaunchCooperativeKernel((void*)stpn_kernel, dim3(256), dim3(1024), args, 0, stream);
}